// Round 1
// baseline (81.044 us; speedup 1.0000x reference)
//
#include <hip/hip_runtime.h>

#define OUT_H 256
#define OUT_W 192
#define NPIX  (OUT_H * OUT_W)   // 49152
#define NB    256
#define NC    25                 // N_CTRL
#define NL    28                 // NC + 3
#define BCHUNK 32

// ---------------------------------------------------------------------------
// Kernel A: build L (28x28) in fp64 and invert via Gauss-Jordan w/ partial
// pivoting. One block, 224 threads = 28 rows x 8 column-groups (7 cols each,
// augmented width 56). Writes Li (28x28 fp32) to ws.
// ---------------------------------------------------------------------------
__global__ __launch_bounds__(224) void tps_invert(float* __restrict__ Li) {
    __shared__ double aug[NL][2 * NL];   // 28 x 56
    __shared__ int spiv;
    const int tid = threadIdx.x;
    const int i  = tid >> 3;             // row 0..27
    const int g  = tid & 7;              // col group 0..7
    const int j0 = g * 7;

    const double axd[5] = {-1.0, -0.5, 0.0, 0.5, 1.0};

    // build [L | I]
    for (int jj = 0; jj < 7; ++jj) {
        int j = j0 + jj;
        double v;
        if (j < NL) {
            if (i < NC && j < NC) {
                double dx = axd[i / 5] - axd[j / 5];
                double dy = axd[i % 5] - axd[j % 5];
                double d2 = dx * dx + dy * dy;
                v = (d2 == 0.0) ? 0.0 : d2 * log(d2);
            } else if (i < NC) {          // j in 25..27 : P columns
                v = (j == NC) ? 1.0 : ((j == NC + 1) ? axd[i / 5] : axd[i % 5]);
            } else if (j < NC) {          // i in 25..27 : P^T rows
                v = (i == NC) ? 1.0 : ((i == NC + 1) ? axd[j / 5] : axd[j % 5]);
            } else {
                v = 0.0;
            }
        } else {
            v = ((j - NL) == i) ? 1.0 : 0.0;
        }
        aug[i][j] = v;
    }
    __syncthreads();

    for (int k = 0; k < NL; ++k) {
        if (tid == 0) {
            int p = k;
            double best = fabs(aug[k][k]);
            for (int r = k + 1; r < NL; ++r) {
                double a = fabs(aug[r][k]);
                if (a > best) { best = a; p = r; }
            }
            spiv = p;
        }
        __syncthreads();
        const int p = spiv;
        if (i == k && p != k) {
            for (int jj = 0; jj < 7; ++jj) {
                int j = j0 + jj;
                double t = aug[k][j]; aug[k][j] = aug[p][j]; aug[p][j] = t;
            }
        }
        __syncthreads();
        const double pv = aug[k][k];
        const double f  = aug[i][k];     // pre-scale multiplier for own row
        __syncthreads();
        if (i == k) {
            for (int jj = 0; jj < 7; ++jj) {
                int j = j0 + jj;
                aug[k][j] /= pv;
            }
        }
        __syncthreads();
        if (i != k) {
            for (int jj = 0; jj < 7; ++jj) {
                int j = j0 + jj;
                aug[i][j] -= f * aug[k][j];
            }
        }
        __syncthreads();
    }

    // right half is the inverse
    for (int jj = 0; jj < 7; ++jj) {
        int j = j0 + jj;
        if (j >= NL) Li[i * NL + (j - NL)] = (float)aug[i][j];
    }
}

// ---------------------------------------------------------------------------
// Kernel B: per-batch coefficients. W_X[25], W_Y[25], A_X[3], A_Y[3] packed
// at stride 64 floats per batch. 256 blocks x 32 threads.
// layout per batch: [0..24]=WX [25..49]=WY [50..52]=AX [53..55]=AY
// ---------------------------------------------------------------------------
__global__ __launch_bounds__(32) void tps_coeff(const float* __restrict__ theta,
                                                const float* __restrict__ Li,
                                                float* __restrict__ Wc) {
    const int b = blockIdx.x;
    const int tid = threadIdx.x;
    __shared__ float qx[NC], qy[NC];
    const float axf[5] = {-1.f, -0.5f, 0.f, 0.5f, 1.f};
    if (tid < NC) {
        qx[tid] = theta[b * 2 * NC + tid]      + axf[tid / 5];
        qy[tid] = theta[b * 2 * NC + NC + tid] + axf[tid % 5];
    }
    __syncthreads();
    if (tid < NL) {
        float sx = 0.f, sy = 0.f;
        #pragma unroll
        for (int m = 0; m < NC; ++m) {
            float l = Li[tid * NL + m];
            sx = fmaf(l, qx[m], sx);
            sy = fmaf(l, qy[m], sy);
        }
        if (tid < NC) {
            Wc[b * 64 + tid]      = sx;
            Wc[b * 64 + NC + tid] = sy;
        } else {
            Wc[b * 64 + 50 + (tid - NC)] = sx;
            Wc[b * 64 + 53 + (tid - NC)] = sy;
        }
    }
}

// ---------------------------------------------------------------------------
// Kernel C: main evaluation. grid = (NPIX/256, NB/BCHUNK). One thread per
// pixel; U[25] computed once in registers, reused over BCHUNK batches.
// Stores coalesced float2 (X', Y').
// ---------------------------------------------------------------------------
__global__ __launch_bounds__(256) void tps_main(const float* __restrict__ Wc,
                                                float2* __restrict__ out) {
    const int p = blockIdx.x * 256 + threadIdx.x;
    const int h = p / OUT_W;
    const int w = p - h * OUT_W;

    // match numpy linspace: double expression, exact endpoints
    const float gx = (w == OUT_W - 1) ? 1.f : (float)(-1.0 + w * (2.0 / (OUT_W - 1)));
    const float gy = (h == OUT_H - 1) ? 1.f : (float)(-1.0 + h * (2.0 / (OUT_H - 1)));

    const float axf[5] = {-1.f, -0.5f, 0.f, 0.5f, 1.f};
    float U[NC];
    #pragma unroll
    for (int n = 0; n < NC; ++n) {
        float dx = gx - axf[n / 5];
        float dy = gy - axf[n % 5];
        float d2 = dx * dx + dy * dy;
        U[n] = (d2 == 0.f) ? 0.f : d2 * logf(d2);
    }

    const int b0 = blockIdx.y * BCHUNK;
    for (int bi = 0; bi < BCHUNK; ++bi) {
        const int b = b0 + bi;
        const float* __restrict__ Wb = Wc + (b << 6);
        float X = fmaf(Wb[52], gy, fmaf(Wb[51], gx, Wb[50]));
        float Y = fmaf(Wb[55], gy, fmaf(Wb[54], gx, Wb[53]));
        #pragma unroll
        for (int n = 0; n < NC; ++n) {
            X = fmaf(U[n], Wb[n],      X);
            Y = fmaf(U[n], Wb[NC + n], Y);
        }
        out[(size_t)b * NPIX + p] = make_float2(X, Y);
    }
}

// ---------------------------------------------------------------------------
extern "C" void kernel_launch(void* const* d_in, const int* in_sizes, int n_in,
                              void* d_out, int out_size, void* d_ws, size_t ws_size,
                              hipStream_t stream) {
    const float* theta = (const float*)d_in[0];
    float* Li = (float*)d_ws;              // 28*28 floats = 3136 B (64B-aligned end)
    float* Wc = Li + NL * NL;              // 256 * 64 floats = 64 KiB

    tps_invert<<<1, 224, 0, stream>>>(Li);
    tps_coeff<<<NB, 32, 0, stream>>>(theta, Li, Wc);
    dim3 grid(NPIX / 256, NB / BCHUNK);
    tps_main<<<grid, 256, 0, stream>>>(Wc, (float2*)d_out);
}

// Round 2
// 77.023 us; speedup vs baseline: 1.0522x; 1.0522x over previous
//
#include <hip/hip_runtime.h>

#define OUT_H 256
#define OUT_W 192
#define NPIX  (OUT_H * OUT_W)   // 49152
#define NB    256
#define NC    25                 // N_CTRL
#define NL    28                 // NC + 3
#define BCHUNK 32

typedef float f2_t __attribute__((ext_vector_type(2)));

// ---------------------------------------------------------------------------
// Fused setup: build L (fp64), Gauss-Jordan invert with wave-parallel pivot
// and virtual row swap (2 barriers/step), then per-batch coefficient GEMV.
// One block, 256 threads.
//   Wc layout per batch (stride 64): [0..24]=WX [25..49]=WY [50..52]=AX [53..55]=AY
// ---------------------------------------------------------------------------
__global__ __launch_bounds__(256) void tps_setup(const float* __restrict__ theta,
                                                 float* __restrict__ Wc) {
    __shared__ double aug[NL][2 * NL + 1];  // 28 x 57 fp64 (pad col)
    __shared__ float  Lif[NL][NL];          // Li fp32, row-stride 28 (112B, 16B-aligned)

    const int tid  = threadIdx.x;
    const int lane = tid & 63;
    const int i    = tid >> 3;              // row 0..31 (rows >=28 idle)
    const int g    = tid & 7;               // col group
    const int j0   = g * 7;
    const bool active = (i < NL);

    const double axd[5] = {-1.0, -0.5, 0.0, 0.5, 1.0};
    const float  axf[5] = {-1.f, -0.5f, 0.f, 0.5f, 1.f};

    // ---- build [L | I] ----
    if (active) {
        for (int jj = 0; jj < 7; ++jj) {
            int j = j0 + jj;
            double v;
            if (j < NL) {
                if (i < NC && j < NC) {
                    double dx = axd[i / 5] - axd[j / 5];
                    double dy = axd[i % 5] - axd[j % 5];
                    double d2 = dx * dx + dy * dy;
                    v = (d2 == 0.0) ? 0.0 : d2 * log(d2);
                } else if (i < NC) {
                    v = (j == NC) ? 1.0 : ((j == NC + 1) ? axd[i / 5] : axd[i % 5]);
                } else if (j < NC) {
                    v = (i == NC) ? 1.0 : ((i == NC + 1) ? axd[j / 5] : axd[j % 5]);
                } else {
                    v = 0.0;
                }
            } else {
                v = ((j - NL) == i) ? 1.0 : 0.0;
            }
            aug[i][j] = v;
        }
    }

    // ---- Gauss-Jordan, 28 steps, 2 barriers each ----
    for (int k = 0; k < NL; ++k) {
        __syncthreads();
        // wave-parallel pivot argmax (all waves compute identically)
        float v  = (lane < NL && lane >= k) ? (float)fabs(aug[lane][k]) : -1.0f;
        int  idx = lane;
        #pragma unroll
        for (int m = 1; m < 64; m <<= 1) {
            float v2 = __shfl_xor(v, m);
            int   i2 = __shfl_xor(idx, m);
            if (v2 > v || (v2 == v && i2 < idx)) { v = v2; idx = i2; }
        }
        const int p = idx;

        // read phase (virtual swap: row k <- old p, row p <- old k)
        double own[7], prow[7], f = 0.0, pv;
        const int src = (i == k) ? p : ((i == p) ? k : i);
        pv = aug[p][k];                       // uniform broadcast read
        if (active) {
            f = aug[src][k];
            #pragma unroll
            for (int jj = 0; jj < 7; ++jj) {
                own[jj]  = aug[src][j0 + jj];
                prow[jj] = aug[p][j0 + jj];
            }
        }
        __syncthreads();
        // write phase
        if (active) {
            const double ipv = 1.0 / pv;
            if (i == k) {
                #pragma unroll
                for (int jj = 0; jj < 7; ++jj) aug[k][j0 + jj] = prow[jj] * ipv;
            } else {
                const double gq = f * ipv;
                #pragma unroll
                for (int jj = 0; jj < 7; ++jj) aug[i][j0 + jj] = own[jj] - gq * prow[jj];
            }
        }
    }
    __syncthreads();

    // ---- Li (right half) -> fp32 LDS ----
    if (active) {
        for (int jj = 0; jj < 7; ++jj) {
            int j = j0 + jj;
            if (j >= NL) Lif[i][j - NL] = (float)aug[i][j];
        }
    }
    __syncthreads();

    // ---- per-batch coefficients: thread b handles batch b ----
    const int b = tid;
    const float* tb = theta + b * 2 * NC;
    float q[2 * NC];
    #pragma unroll
    for (int m = 0; m < NC; ++m) {
        q[m]      = tb[m]      + axf[m / 5];   // Q_X
        q[NC + m] = tb[NC + m] + axf[m % 5];   // Q_Y
    }
    float* wb = Wc + (b << 6);
    #pragma unroll
    for (int n = 0; n < NL; ++n) {
        float sx = 0.f, sy = 0.f;
        #pragma unroll
        for (int m = 0; m < NC; ++m) {
            float l = Lif[n][m];
            sx = fmaf(l, q[m],      sx);
            sy = fmaf(l, q[NC + m], sy);
        }
        if (n < NC) {
            wb[n]      = sx;
            wb[NC + n] = sy;
        } else {
            wb[50 + (n - NC)] = sx;
            wb[53 + (n - NC)] = sy;
        }
    }
}

// ---------------------------------------------------------------------------
// Main evaluation. grid = (NPIX/256, NB/BCHUNK). One thread per pixel;
// U[25] in registers, reused over BCHUNK batches. Wave-uniform Wc reads
// (scalar loads), nontemporal coalesced float2 stores.
// ---------------------------------------------------------------------------
__global__ __launch_bounds__(256) void tps_main(const float* __restrict__ Wc,
                                                float2* __restrict__ out) {
    const int p = blockIdx.x * 256 + threadIdx.x;
    const int h = p / OUT_W;
    const int w = p - h * OUT_W;

    const float gx = (w == OUT_W - 1) ? 1.f : (float)(-1.0 + w * (2.0 / (OUT_W - 1)));
    const float gy = (h == OUT_H - 1) ? 1.f : (float)(-1.0 + h * (2.0 / (OUT_H - 1)));

    const float axf[5] = {-1.f, -0.5f, 0.f, 0.5f, 1.f};
    float U[NC];
    #pragma unroll
    for (int n = 0; n < NC; ++n) {
        float dx = gx - axf[n / 5];
        float dy = gy - axf[n % 5];
        float d2 = dx * dx + dy * dy;
        U[n] = (d2 == 0.f) ? 0.f : d2 * logf(d2);
    }

    const int b0 = blockIdx.y * BCHUNK;
    for (int bi = 0; bi < BCHUNK; ++bi) {
        const int b = b0 + bi;
        const float* __restrict__ Wb = Wc + (b << 6);
        float X = fmaf(Wb[52], gy, fmaf(Wb[51], gx, Wb[50]));
        float Y = fmaf(Wb[55], gy, fmaf(Wb[54], gx, Wb[53]));
        #pragma unroll
        for (int n = 0; n < NC; ++n) {
            X = fmaf(U[n], Wb[n],      X);
            Y = fmaf(U[n], Wb[NC + n], Y);
        }
        f2_t val; val.x = X; val.y = Y;
        __builtin_nontemporal_store(val, (f2_t*)&out[(size_t)b * NPIX + p]);
    }
}

// ---------------------------------------------------------------------------
extern "C" void kernel_launch(void* const* d_in, const int* in_sizes, int n_in,
                              void* d_out, int out_size, void* d_ws, size_t ws_size,
                              hipStream_t stream) {
    const float* theta = (const float*)d_in[0];
    float* Wc = (float*)d_ws;              // 256 * 64 floats = 64 KiB

    tps_setup<<<1, 256, 0, stream>>>(theta, Wc);
    dim3 grid(NPIX / 256, NB / BCHUNK);
    tps_main<<<grid, 256, 0, stream>>>(Wc, (float2*)d_out);
}

// Round 3
// 36.869 us; speedup vs baseline: 2.1982x; 2.0891x over previous
//
#include <hip/hip_runtime.h>

#define OUT_H 256
#define OUT_W 192
#define NPIX  (OUT_H * OUT_W)   // 49152
#define NB    256
#define NC    25                 // N_CTRL
#define NL    28                 // NC + 3
#define BCHUNK 32

typedef float f4_t __attribute__((ext_vector_type(4)));

// ---------------------------------------------------------------------------
// Compile-time Li = inv(L) (first NC columns), fp64 Gauss-Jordan w/ partial
// pivoting, evaluated by the compiler. cx_log: ln via atanh series (~1e-16).
// ---------------------------------------------------------------------------
constexpr double cx_log(double x) {
    int k = 0;
    while (x > 1.5) { x *= 0.5; ++k; }
    while (x < 0.75) { x *= 2.0; --k; }
    double z = (x - 1.0) / (x + 1.0);
    double z2 = z * z;
    double t = z, s = 0.0;
    for (int i = 0; i < 16; ++i) { s += t / (double)(2 * i + 1); t *= z2; }
    return 2.0 * s + (double)k * 0.69314718055994530941723212145817656808;
}

struct LiMat { float v[NL][NC]; };

constexpr LiMat make_li() {
    double aug[NL][2 * NL] = {};
    const double ax[5] = {-1.0, -0.5, 0.0, 0.5, 1.0};
    for (int i = 0; i < NL; ++i)
        for (int j = 0; j < NL; ++j) {
            double v = 0.0;
            if (i < NC && j < NC) {
                double dx = ax[i / 5] - ax[j / 5];
                double dy = ax[i % 5] - ax[j % 5];
                double d2 = dx * dx + dy * dy;
                v = (d2 == 0.0) ? 0.0 : d2 * cx_log(d2);
            } else if (i < NC) {
                v = (j == NC) ? 1.0 : ((j == NC + 1) ? ax[i / 5] : ax[i % 5]);
            } else if (j < NC) {
                v = (i == NC) ? 1.0 : ((i == NC + 1) ? ax[j / 5] : ax[j % 5]);
            }
            aug[i][j] = (double)(float)v;   // mimic numpy's fp32 L build
        }
    for (int i = 0; i < NL; ++i) aug[i][NL + i] = 1.0;

    for (int k = 0; k < NL; ++k) {
        int p = k;
        double best = aug[k][k] < 0 ? -aug[k][k] : aug[k][k];
        for (int r = k + 1; r < NL; ++r) {
            double a = aug[r][k] < 0 ? -aug[r][k] : aug[r][k];
            if (a > best) { best = a; p = r; }
        }
        if (p != k)
            for (int j = k; j < 2 * NL; ++j) {
                double t = aug[k][j]; aug[k][j] = aug[p][j]; aug[p][j] = t;
            }
        const double ipv = 1.0 / aug[k][k];
        for (int j = k; j < 2 * NL; ++j) aug[k][j] *= ipv;
        for (int r = 0; r < NL; ++r) {
            if (r == k) continue;
            const double f = aug[r][k];
            if (f == 0.0) continue;
            for (int j = k; j < 2 * NL; ++j) aug[r][j] -= f * aug[k][j];
        }
    }
    LiMat o = {};
    for (int i = 0; i < NL; ++i)
        for (int j = 0; j < NC; ++j)
            o.v[i][j] = (float)aug[i][NL + j];
    return o;
}

constexpr LiMat LI_HOST = make_li();
__constant__ LiMat LI = LI_HOST;          // 2.8 KB, baked at compile time
__constant__ float WC[NB * 64];           // 64 KB, written by tps_coeff each call
// per-batch layout (stride 64): [0..24]=WX [25..49]=WY [50..52]=AX [53..55]=AY

// ---------------------------------------------------------------------------
// Per-batch coefficients. 4 blocks x 64 threads; thread = one batch.
// theta staged through LDS for coalesced global reads; Li via s_load.
// ---------------------------------------------------------------------------
__global__ __launch_bounds__(64) void tps_coeff(const float* __restrict__ theta,
                                                float* __restrict__ wc) {
    __shared__ float sth[64 * 2 * NC];
    const int t = threadIdx.x;
    const int gbase = blockIdx.x * 64 * 2 * NC;
    #pragma unroll
    for (int k = 0; k < 2 * NC; ++k) {
        const int idx = k * 64 + t;
        sth[idx] = theta[gbase + idx];
    }
    __syncthreads();

    const float axf[5] = {-1.f, -0.5f, 0.f, 0.5f, 1.f};
    float q[2 * NC];
    #pragma unroll
    for (int m = 0; m < NC; ++m) {
        q[m]      = sth[t * 2 * NC + m]      + axf[m / 5];
        q[NC + m] = sth[t * 2 * NC + NC + m] + axf[m % 5];
    }

    float* wb = wc + ((blockIdx.x * 64 + t) << 6);
    #pragma unroll
    for (int n = 0; n < NL; ++n) {
        float sx = 0.f, sy = 0.f;
        #pragma unroll
        for (int m = 0; m < NC; ++m) {
            const float l = LI.v[n][m];
            sx = fmaf(l, q[m],      sx);
            sy = fmaf(l, q[NC + m], sy);
        }
        if (n < NC) { wb[n] = sx; wb[NC + n] = sy; }
        else        { wb[50 + (n - NC)] = sx; wb[53 + (n - NC)] = sy; }
    }
}

// ---------------------------------------------------------------------------
// Main evaluation. grid = (96, 8), 256 threads. Two adjacent pixels per
// thread; U[25] x2 in registers, reused over BCHUNK batches. Coefficients
// read from __constant__ (uniform index -> s_load -> SGPR operands).
// float4 nontemporal coalesced stores.
// ---------------------------------------------------------------------------
__global__ __launch_bounds__(256) void tps_main(f4_t* __restrict__ out4) {
    const int pp = blockIdx.x * 256 + threadIdx.x;     // pixel-pair 0..24575
    const int h  = pp / (OUT_W / 2);
    const int w0 = (pp - h * (OUT_W / 2)) * 2;

    const float gy  = (h == OUT_H - 1) ? 1.f : (float)(-1.0 + h * (2.0 / (OUT_H - 1)));
    const float gx0 = (float)(-1.0 + w0 * (2.0 / (OUT_W - 1)));
    const float gx1 = (w0 + 1 == OUT_W - 1) ? 1.f
                                            : (float)(-1.0 + (w0 + 1) * (2.0 / (OUT_W - 1)));

    const float axf[5] = {-1.f, -0.5f, 0.f, 0.5f, 1.f};
    float U0[NC], U1[NC];
    #pragma unroll
    for (int n = 0; n < NC; ++n) {
        const float cx = axf[n / 5], cy = axf[n % 5];
        const float dy  = gy - cy;
        const float dx0 = gx0 - cx;
        const float d20 = dx0 * dx0 + dy * dy;
        U0[n] = (d20 == 0.f) ? 0.f : d20 * logf(d20);
        const float dx1 = gx1 - cx;
        const float d21 = dx1 * dx1 + dy * dy;
        U1[n] = (d21 == 0.f) ? 0.f : d21 * logf(d21);
    }

    const int b0 = blockIdx.y * BCHUNK;
    for (int bi = 0; bi < BCHUNK; ++bi) {
        const int b = b0 + bi;
        const int o = b << 6;
        float X0 = fmaf(WC[o + 52], gy, fmaf(WC[o + 51], gx0, WC[o + 50]));
        float X1 = fmaf(WC[o + 52], gy, fmaf(WC[o + 51], gx1, WC[o + 50]));
        float Y0 = fmaf(WC[o + 55], gy, fmaf(WC[o + 54], gx0, WC[o + 53]));
        float Y1 = fmaf(WC[o + 55], gy, fmaf(WC[o + 54], gx1, WC[o + 53]));
        #pragma unroll
        for (int n = 0; n < NC; ++n) {
            const float wx = WC[o + n];
            const float wy = WC[o + NC + n];
            X0 = fmaf(U0[n], wx, X0);
            X1 = fmaf(U1[n], wx, X1);
            Y0 = fmaf(U0[n], wy, Y0);
            Y1 = fmaf(U1[n], wy, Y1);
        }
        f4_t v; v.x = X0; v.y = Y0; v.z = X1; v.w = Y1;
        __builtin_nontemporal_store(v, &out4[(size_t)b * (NPIX / 2) + pp]);
    }
}

// ---------------------------------------------------------------------------
extern "C" void kernel_launch(void* const* d_in, const int* in_sizes, int n_in,
                              void* d_out, int out_size, void* d_ws, size_t ws_size,
                              hipStream_t stream) {
    const float* theta = (const float*)d_in[0];

    void* wcsym = nullptr;
    hipGetSymbolAddress(&wcsym, HIP_SYMBOL(WC));   // host-side query, capture-safe

    tps_coeff<<<NB / 64, 64, 0, stream>>>(theta, (float*)wcsym);
    dim3 grid(NPIX / 2 / 256, NB / BCHUNK);        // (96, 8)
    tps_main<<<grid, 256, 0, stream>>>((f4_t*)d_out);
}